// Round 2
// baseline (3486.207 us; speedup 1.0000x reference)
//
#include <hip/hip_runtime.h>
#include <hip/hip_bf16.h>

#define HH 512
#define VV 50257
#define BB 64
#define TL 512
#define NG 8     // batch groups
#define NS 8     // column slices (blocks) per group
#define MB 8     // batches per group
#define NTHR 256

typedef __attribute__((ext_vector_type(8))) short short8;
typedef __attribute__((ext_vector_type(4))) float floatx4;

__device__ __forceinline__ unsigned short f2bf(float f) {
  union { float f; unsigned int u; } v; v.f = f;
  unsigned int r = (v.u + 0x7fffu + ((v.u >> 16) & 1u)) >> 16;
  return (unsigned short)r;
}

// ---- P1: column max of alpha_exp (+eps) and its log ----
__global__ void colmaxK(const float* __restrict__ A, float* __restrict__ cmax,
                        float* __restrict__ wmax) {
  __shared__ float red[4][64];
  int x = threadIdx.x & 63;
  int y = threadIdx.x >> 6;
  int c = blockIdx.x * 64 + x;
  float m = -INFINITY;
  for (int j = y; j < HH; j += 4) m = fmaxf(m, A[j * HH + c]);
  red[y][x] = m;
  __syncthreads();
  if (y == 0) {
    m = fmaxf(fmaxf(red[0][x], red[1][x]), fmaxf(red[2][x], red[3][x])) + 1e-12f;
    cmax[c] = m;
    wmax[c] = __logf(m);
  }
}

// ---- P2: build bf16 Wn pre-swizzled into MFMA B-fragment lane order ----
// Wf flat index = (((s*4 + w)*16 + k)*64 + L) holding 8 bf16 (j=0..7):
//   element = Wn[32k + (L>>4)*8 + j][s*64 + w*16 + (L&15)]
__global__ void buildWfK(const float* __restrict__ A, const float* __restrict__ cmax,
                         uint4* __restrict__ Wf) {
  int gid = blockIdx.x * 256 + threadIdx.x;  // 0..32767
  int s = gid >> 12;
  int w = (gid >> 10) & 3;
  int k = (gid >> 6) & 15;
  int L = gid & 63;
  int n = s * 64 + w * 16 + (L & 15);
  int k0 = 32 * k + (L >> 4) * 8;
  float inv = 1.0f / cmax[n];
  alignas(16) unsigned short o[8];
#pragma unroll
  for (int j = 0; j < 8; ++j)
    o[j] = f2bf((A[(k0 + j) * HH + n] + 1e-12f) * inv);
  Wf[gid] = *(const uint4*)o;
}

// ---- P3: transpose beta (H,V) -> betaT (V,H), f32 ----
__global__ void transposeBeta(const float* __restrict__ beta, float* __restrict__ betaT) {
  __shared__ float tile[32][33];
  int v0 = blockIdx.x * 32, h0 = blockIdx.y * 32;
  int tx = threadIdx.x, ty = threadIdx.y;
#pragma unroll
  for (int k = 0; k < 4; ++k) {
    int v = v0 + tx;
    if (v < VV) tile[ty + 8 * k][tx] = beta[(h0 + ty + 8 * k) * VV + v];
  }
  __syncthreads();
#pragma unroll
  for (int k = 0; k < 4; ++k) {
    int v = v0 + ty + 8 * k;
    if (v < VV) betaT[(long)v * HH + h0 + tx] = tile[tx][ty + 8 * k];
  }
}

// ---- Main: 64 persistent blocks = 8 groups x 8 slices; per-step slice exchange ----
__global__ __launch_bounds__(NTHR, 1)
void hmm_main(const uint4* __restrict__ Wf,
              const float* __restrict__ wmax,
              const float* __restrict__ betaSrc, long bs1, long bs2,
              const int* __restrict__ ids,
              const float* __restrict__ gamma,
              float* __restrict__ alphaex,   // [2][NG][MB][HH]
              float* __restrict__ maxex,     // [2][NG][NS][MB]
              int* __restrict__ flags,       // [NG*NS] spaced 16 ints
              float* __restrict__ out) {
  const int g = blockIdx.x & 7;
  const int s = blockIdx.x >> 3;
  const int tid = threadIdx.x;
  const int w = tid >> 6;
  const int L = tid & 63;
  const int lane16 = L & 15;
  const int quad = L >> 4;
  const int rq = (quad & 1) * 4;   // epilogue row base (quads 2,3 hold pad rows 8..15)
  const bool qok = quad < 2;

  __shared__ unsigned short xA[16 * 520];  // A tile, rows padded +8 elems (bank spread)
  __shared__ float wpart[4][8];
  __shared__ float gsh[8];

  for (int r = 8; r < 16; ++r)
    for (int c = tid; c < 520; c += NTHR) xA[r * 520 + c] = 0;  // pad batch rows

  // W fragments -> registers (64 VGPR/lane), fully coalesced load
  short8 wreg[16];
  {
    const uint4* wp = Wf + ((s * 4 + w) * 16) * 64 + L;
#pragma unroll
    for (int k = 0; k < 16; ++k) wreg[k] = __builtin_bit_cast(short8, wp[k * 64]);
  }

  const int ncol = s * 64 + w * 16 + lane16;  // this lane's output column
  const float wmaxv = wmax[ncol];

  // ---- t = 0: alpha0 slice ----
  {
    const int r = tid >> 5;
    const int c0 = s * 64 + (tid & 31) * 2;
    const int id0 = ids[(g * MB + r) * TL];
    float a0 = __logf(gamma[c0]) + betaSrc[(long)id0 * bs1 + (long)c0 * bs2];
    float a1 = __logf(gamma[c0 + 1]) + betaSrc[(long)id0 * bs1 + (long)(c0 + 1) * bs2];
    float* dst = alphaex + (0 * NG + g) * (MB * HH) + r * HH;
    dst[c0] = a0;
    dst[c0 + 1] = a1;
    float m = fmaxf(a0, a1);
#pragma unroll
    for (int msk = 1; msk <= 16; msk <<= 1) m = fmaxf(m, __shfl_xor(m, msk));
    if ((tid & 31) == 0) maxex[(0 * NG + g) * (NS * MB) + s * MB + r] = m;
  }
  __syncthreads();
  if (tid == 0) {
    __builtin_amdgcn_fence(__ATOMIC_RELEASE, "agent");
    __hip_atomic_store(&flags[(g * NS + s) * 16], 1, __ATOMIC_RELAXED, __HIP_MEMORY_SCOPE_AGENT);
  }

  for (int t = 1; t < TL; ++t) {
    const int pr = (t - 1) & 1;
    const int pw = t & 1;

    // Phase A: prefetch emission log-probs for this lane's output rows/col
    float betav[4];
#pragma unroll
    for (int i = 0; i < 4; ++i) {
      int id = ids[(g * MB + rq + i) * TL + t];
      betav[i] = betaSrc[(long)id * bs1 + (long)ncol * bs2];
    }

    // Phase B: wait for all 8 slices of alpha_{t-1}; monotonic flags (0xAA poison < 1)
    for (int sig = 0; sig < NS; ++sig) {
      int spin = 0;
      while (__hip_atomic_load(&flags[(g * NS + sig) * 16], __ATOMIC_RELAXED,
                               __HIP_MEMORY_SCOPE_AGENT) < t) {
        __builtin_amdgcn_s_sleep(1);
        if (++spin > (1 << 22)) break;  // safety valve: corrupt, not hung
      }
    }
    __builtin_amdgcn_fence(__ATOMIC_ACQUIRE, "agent");

    // Read exchange, compute global row-max, exp, pack bf16 into A-layout LDS
    const int r = tid >> 5;
    const int c0 = (tid & 31) * 16;
    float gmax = -INFINITY;
#pragma unroll
    for (int sig = 0; sig < NS; ++sig)
      gmax = fmaxf(gmax, maxex[(pr * NG + g) * (NS * MB) + sig * MB + r]);
    if ((tid & 31) == 0) gsh[r] = gmax;

    const float* arow = alphaex + (pr * NG + g) * (MB * HH) + r * HH + c0;
    float av[16];
#pragma unroll
    for (int i = 0; i < 4; ++i) {
      float4 v = ((const float4*)arow)[i];
      av[4 * i + 0] = v.x; av[4 * i + 1] = v.y; av[4 * i + 2] = v.z; av[4 * i + 3] = v.w;
    }
    alignas(16) unsigned short xv[16];
#pragma unroll
    for (int i = 0; i < 16; ++i)
      xv[i] = f2bf(__expf(fminf(av[i] - gmax, 0.f)));  // clamp exact: gmax >= av
    *(uint4*)&xA[r * 520 + c0] = *(const uint4*)&xv[0];
    *(uint4*)&xA[r * 520 + c0 + 8] = *(const uint4*)&xv[8];
    __syncthreads();

    // Phase C: Z = X @ Wn ; B from registers, A from LDS
    floatx4 acc = {0.f, 0.f, 0.f, 0.f};
#pragma unroll
    for (int k = 0; k < 16; ++k) {
      short8 af = *(const short8*)&xA[lane16 * 520 + k * 32 + quad * 8];
      acc = __builtin_amdgcn_mfma_f32_16x16x32_bf16(af, wreg[k], acc, 0, 0, 0);
    }

    // Phase D: epilogue — alpha_new = log z + shift + wmax + beta
    float anew[4], rm[4];
#pragma unroll
    for (int i = 0; i < 4; ++i)
      anew[i] = __logf(fmaxf(acc[i], 1e-37f)) + gsh[rq + i] + wmaxv + betav[i];
#pragma unroll
    for (int i = 0; i < 4; ++i) {
      float m = anew[i];
#pragma unroll
      for (int msk = 1; msk <= 8; msk <<= 1) m = fmaxf(m, __shfl_xor(m, msk));
      rm[i] = m;
    }
    if (qok && lane16 == 0) {
#pragma unroll
      for (int i = 0; i < 4; ++i) wpart[w][rq + i] = rm[i];
    }
    float* aw = alphaex + (pw * NG + g) * (MB * HH);
    if (qok) {
#pragma unroll
      for (int i = 0; i < 4; ++i) {
        aw[(rq + i) * HH + ncol] = anew[i];
        if (t == TL - 1) out[(g * MB + rq + i) * HH + ncol] = anew[i];
      }
    }
    __syncthreads();
    if (tid < 8) {
      float m = fmaxf(fmaxf(wpart[0][tid], wpart[1][tid]),
                      fmaxf(wpart[2][tid], wpart[3][tid]));
      maxex[(pw * NG + g) * (NS * MB) + s * MB + tid] = m;
    }
    __syncthreads();
    if (tid == 0) {
      __builtin_amdgcn_fence(__ATOMIC_RELEASE, "agent");
      __hip_atomic_store(&flags[(g * NS + s) * 16], t + 1, __ATOMIC_RELAXED,
                         __HIP_MEMORY_SCOPE_AGENT);
    }
  }
}

extern "C" void kernel_launch(void* const* d_in, const int* in_sizes, int n_in,
                              void* d_out, int out_size, void* d_ws, size_t ws_size,
                              hipStream_t stream) {
  const float* alpha_exp = (const float*)d_in[0];
  const float* beta = (const float*)d_in[1];
  const float* gamma = (const float*)d_in[2];
  const int* ids = (const int*)d_in[3];
  float* out = (float*)d_out;

  // Workspace map (no overlaps — R1's bug was flags aliasing maxex[1]):
  char* ws = (char*)d_ws;
  float* cmax    = (float*)(ws + 0);        // [  0      ,   2048)
  float* wmax    = (float*)(ws + 2048);     // [  2048   ,   4096)
  uint4* Wf      = (uint4*)(ws + 4096);     // [  4096   , 528384)  512 KB
  float* alphaex = (float*)(ws + 528384);   // [528384   , 790528)  256 KB (2x dbuf)
  float* maxex   = (float*)(ws + 790528);   // [790528   , 794624)  4 KB   (2x dbuf)
  int*   flags   = (int*)(ws + 794624);     // [794624   , 798720)  4 KB
  float* betaT   = (float*)(ws + 798720);   // 102.9 MB (optional)
  const size_t need_full = 798720ull + (size_t)VV * HH * 4ull;

  colmaxK<<<8, 256, 0, stream>>>(alpha_exp, cmax, wmax);
  buildWfK<<<128, 256, 0, stream>>>(alpha_exp, cmax, Wf);

  const float* betaSrc;
  long bs1, bs2;
  if (ws_size >= need_full) {
    dim3 gT((VV + 31) / 32, HH / 32), bT(32, 8);
    transposeBeta<<<gT, bT, 0, stream>>>(beta, betaT);
    betaSrc = betaT; bs1 = HH; bs2 = 1;
  } else {
    betaSrc = beta; bs1 = 1; bs2 = VV;  // strided fallback if ws too small
  }

  hmm_main<<<NG * NS, NTHR, 0, stream>>>(Wf, wmax, betaSrc, bs1, bs2, ids, gamma,
                                         alphaex, maxex, flags, out);
}